// Round 15
// baseline (428.600 us; speedup 1.0000x reference)
//
#include <hip/hip_runtime.h>
#include <hip/hip_bf16.h>
#include <stdint.h>

#define Bb 8
#define Nn 1500
#define Ee 3000
#define Hh 256
#define NHOPS 3
#define CAP 32
#define Mrows (Bb*Nn)      // 12000
#define BE (Bb*Ee)         // 24000
#define BN (Bb*Nn)         // 12000
#define TOTQ 9000000       // float4 per incidence matrix
#define NELEM1 36000000    // elements in n2e
#define PAIRBUF (1<<20)

typedef __bf16 bf16x8 __attribute__((ext_vector_type(8)));
typedef float f32x4 __attribute__((ext_vector_type(4)));
typedef float nf4 __attribute__((ext_vector_type(4)));   // native vec for nontemporal builtin

__device__ __forceinline__ float sigmoidf_(float x){ return 1.f/(1.f+__expf(-x)); }

__device__ __forceinline__ unsigned short f2b(float f){
  union { float f; unsigned int u; } x; x.f = f;
  unsigned int r = (x.u + 0x7fffu + ((x.u >> 16) & 1u)) >> 16;
  return (unsigned short)r;
}
__device__ __forceinline__ float b2f(unsigned short u){
  union { unsigned int u; float f; } x; x.u = ((unsigned int)u) << 16;
  return x.f;
}
__device__ __forceinline__ ushort4 pack4(float4 v){
  return make_ushort4(f2b(v.x), f2b(v.y), f2b(v.z), f2b(v.w));
}
__device__ __forceinline__ float4 unpack4(ushort4 u){
  return make_float4(b2f(u.x), b2f(u.y), b2f(u.z), b2f(u.w));
}
__device__ __forceinline__ unsigned fkey(float f){
  unsigned u = __float_as_uint(f);
  return (u & 0x80000000u) ? ~u : (u | 0x80000000u);
}

// async global->LDS, 16B per lane; LDS dest = uniform base + lane*16
#define GLL16(g, l) __builtin_amdgcn_global_load_lds( \
    (const __attribute__((address_space(1))) unsigned int*)(g), \
    (__attribute__((address_space(3))) unsigned int*)(l), 16, 0, 0)

// ---------- preprocess megakernel ----------
// scan: pure stream + LDS compaction; one global atomic per block.
//  [0,8790)          both incidence scans, 8 quads/thread (18,000,000 quads)
//  [8790,11350)      weight prep (655360 elems)
//  [11350,12100)     in_ns f32 -> nsb bf16 (768,000 f4)
//  [12100,13600)     edge_vec f32 -> bf16 (1,536,000 f4)
__global__ void preprocess_kernel(const nf4* __restrict__ n2e4, const nf4* __restrict__ e2n4,
                                  int* __restrict__ gpairs, int* __restrict__ gpaircnt,
                                  const float* __restrict__ Wfz, const float* __restrict__ Wz,
                                  const float* __restrict__ Wr, const float* __restrict__ Wt,
                                  const float* __restrict__ Wmax,
                                  unsigned short* __restrict__ WfzT, unsigned short* __restrict__ WzrT,
                                  unsigned short* __restrict__ WtT, unsigned short* __restrict__ WmaxT,
                                  const float* __restrict__ in_ns, unsigned short* __restrict__ nsb,
                                  const float* __restrict__ in_ev, unsigned short* __restrict__ evb) {
  __shared__ int lcnt, lbase;
  __shared__ int lpairs[512];
  int bx = blockIdx.x;
  if (bx < 8790) {
    if (threadIdx.x == 0) lcnt = 0;
    __syncthreads();
    int t0 = bx * 2048 + threadIdx.x;
    nf4 v[8];
    #pragma unroll
    for (int r2 = 0; r2 < 8; ++r2) {
      int t = t0 + r2 * 256;
      const nf4* p = (t < TOTQ) ? (n2e4 + t) : (e2n4 + (t - TOTQ));
      if (t < 2 * TOTQ) v[r2] = __builtin_nontemporal_load(p);
      else { v[r2].x = 0.f; v[r2].y = 0.f; v[r2].z = 0.f; v[r2].w = 0.f; }
    }
    __builtin_amdgcn_sched_barrier(0);   // loads may not sink past this
    #pragma unroll
    for (int r2 = 0; r2 < 8; ++r2) {
      nf4 vv = v[r2];
      if (vv.x != 0.f || vv.y != 0.f || vv.z != 0.f || vv.w != 0.f) {
        int t = t0 + r2 * 256;
        #pragma unroll
        for (int j = 0; j < 4; ++j) {
          float vj = (j == 0) ? vv.x : (j == 1) ? vv.y : (j == 2) ? vv.z : vv.w;
          if (vj != 0.f) {
            int p = atomicAdd(&lcnt, 1);
            if (p < 512) lpairs[p] = t * 4 + j;
          }
        }
      }
    }
    __syncthreads();
    int n = min(lcnt, 512);
    if (threadIdx.x == 0) lbase = (n > 0) ? atomicAdd(gpaircnt, n) : 0;
    __syncthreads();
    for (int i = threadIdx.x; i < n; i += 256) {
      int dst = lbase + i;
      if (dst < PAIRBUF) gpairs[dst] = lpairs[i];
    }
  } else if (bx < 11350) {
    int t = (bx - 8790) * 256 + threadIdx.x;
    if (t < 196608) {                       // WfzT': 256 n x 768 k (combined)
      int n = t / 768, k = t % 768;
      float v;
      if (k < 256)      v = Wfz[k * 256 + n] + Wfz[(k + 768) * 256 + n];
      else if (k < 512) v = Wfz[k * 256 + n] - Wfz[(k + 512) * 256 + n];
      else              v = Wfz[k * 256 + n];
      WfzT[t] = f2b(v);
    } else if (t < 458752) {                // WzrT: 512 j x 512 k
      int u = t - 196608;
      int j = u >> 9, k = u & 511;
      float v = (j < 256) ? Wz[k * 256 + j] : Wr[k * 256 + (j - 256)];
      WzrT[u] = f2b(v);
    } else if (t < 589824) {                // WtT: 256 n x 512 k
      int u = t - 458752;
      int n = u >> 9, k = u & 511;
      WtT[u] = f2b(Wt[k * 256 + n]);
    } else if (t < 655360) {                // WmaxT: 256 x 256
      int u = t - 589824;
      int n = u >> 8, k = u & 255;
      WmaxT[u] = f2b(Wmax[k * 256 + n]);
    }
  } else if (bx < 12100) {
    int t0 = (bx - 11350) * 1024 + threadIdx.x;   // 768000 f4
    #pragma unroll
    for (int r = 0; r < 4; ++r) {
      int t = t0 + r * 256;
      ((ushort4*)nsb)[t] = pack4(((const float4*)in_ns)[t]);
    }
  } else {
    int t0 = (bx - 12100) * 1024 + threadIdx.x;   // 1536000 f4
    #pragma unroll
    for (int r = 0; r < 4; ++r) {
      int t = t0 + r * 256;
      ((ushort4*)evb)[t] = pack4(((const float4*)in_ev)[t]);
    }
  }
}

// ---------- phase B: scatter compacted nonzeros into the 4 adjacency lists ----------
__global__ void pairscatter_kernel(const int* __restrict__ gpairs, const int* __restrict__ gpaircnt,
                                   int* __restrict__ Aidx, int* __restrict__ cntA,
                                   int* __restrict__ Didx, int* __restrict__ cntD,
                                   int* __restrict__ Bidx, int* __restrict__ cntB,
                                   int* __restrict__ Cidx, int* __restrict__ cntC) {
  int n = min(*gpaircnt, PAIRBUF);
  for (int i = blockIdx.x * 256 + threadIdx.x; i < n; i += 1024 * 256) {
    int e = gpairs[i];
    if (e < NELEM1) {                  // n2e (B,E,N): g = b*E+e_, c = node
      int g = e / Nn;
      int c = e - g * Nn;
      int b = g / Ee;
      int r = g - b * Ee;
      int rs = atomicAdd(&cntA[g], 1);
      if (rs < CAP) Aidx[(size_t)g * CAP + rs] = c;
      int cs = atomicAdd(&cntD[b * Nn + c], 1);
      if (cs < CAP) Didx[(size_t)(b * Nn + c) * CAP + cs] = r;
    } else {                           // e2n (B,N,E): g = b*N+n, c = edge
      int u = e - NELEM1;
      int g = u / Ee;
      int c = u - g * Ee;
      int b = g / Nn;
      int r = g - b * Nn;
      int rs = atomicAdd(&cntB[g], 1);
      if (rs < CAP) Bidx[(size_t)g * CAP + rs] = c;
      int cs = atomicAdd(&cntC[b * Ee + c], 1);
      if (cs < CAP) Cidx[(size_t)(b * Ee + c) * CAP + cs] = r;
    }
  }
}

__device__ __forceinline__ void sort_one(int* pp, int c) {
  if (c > CAP) c = CAP;
  int v[CAP];
  for (int j = 0; j < c; ++j) v[j] = pp[j];
  for (int j = 1; j < c; ++j) { int key = v[j]; int k = j - 1;
    while (k >= 0 && v[k] > key) { v[k+1] = v[k]; --k; } v[k+1] = key; }
  for (int j = 0; j < c; ++j) pp[j] = v[j];
}
// sorts all four list families (72000 lists)
__global__ void sort4_kernel(int* __restrict__ Cidx, const int* __restrict__ cntC,
                             int* __restrict__ Didx, const int* __restrict__ cntD,
                             int* __restrict__ Aidx, const int* __restrict__ cntA,
                             int* __restrict__ Bidx, const int* __restrict__ cntB) {
  int i = blockIdx.x * 256 + threadIdx.x;
  if (i < BE) sort_one(Cidx + (size_t)i * CAP, cntC[i]);
  else if (i < BE + BN) { int k = i - BE; sort_one(Didx + (size_t)k * CAP, cntD[k]); }
  else if (i < 2 * BE + BN) { int k = i - BE - BN; sort_one(Aidx + (size_t)k * CAP, cntA[k]); }
  else if (i < 2 * BE + 2 * BN) { int k = i - 2 * BE - BN; sort_one(Bidx + (size_t)k * CAP, cntB[k]); }
}

// ---------- per-hop: edge embedding (both directions), bf16 gathers, 4 edges/block ----------
__global__ void edge_kernel(const ushort4* __restrict__ evb4, const ushort4* __restrict__ nsb4,
                            const int* __restrict__ Aidx, const int* __restrict__ Acnt,
                            const int* __restrict__ Cidx, const int* __restrict__ Ccnt,
                            ushort4* __restrict__ eb4, ushort4* __restrict__ ef4) {
  int w = __builtin_amdgcn_readfirstlane((int)(threadIdx.x >> 6));
  int be = blockIdx.x * 4 + w;
  int lane = threadIdx.x & 63;
  int b = be / Ee;
  int cA = min(Acnt[be], CAP), cC = min(Ccnt[be], CAP);
  const int* pA = Aidx + (size_t)be * CAP;
  const int* pC = Cidx + (size_t)be * CAP;
  float4 ev = unpack4(evb4[(size_t)be * 64 + lane]);
  float4 sA = ev, sC = ev;
  for (int i = 0; i < cA; ++i) {
    int n = pA[i];
    float4 t = unpack4(nsb4[((size_t)b * Nn + n) * 64 + lane]);
    sA.x += t.x; sA.y += t.y; sA.z += t.z; sA.w += t.w;
  }
  for (int i = 0; i < cC; ++i) {
    int n = pC[i];
    float4 t = unpack4(nsb4[((size_t)b * Nn + n) * 64 + lane]);
    sC.x += t.x; sC.y += t.y; sC.z += t.z; sC.w += t.w;
  }
  eb4[(size_t)be * 64 + lane] = pack4(sA);
  ef4[(size_t)be * 64 + lane] = pack4(sC);
}

// ---------- per-hop: node aggregation + build Xfz (bf16 h from nsb) ----------
__global__ void node_kernel(const ushort4* __restrict__ nsb4,
                            const ushort4* __restrict__ eb4, const ushort4* __restrict__ ef4,
                            const int* __restrict__ Bidx, const int* __restrict__ Bcnt,
                            const int* __restrict__ Didx, const int* __restrict__ Dcnt,
                            ushort4* __restrict__ Xfz4) {
  int w = __builtin_amdgcn_readfirstlane((int)(threadIdx.x >> 6));
  int bn = blockIdx.x * 4 + w;
  int lane = threadIdx.x & 63;
  int b = bn / Nn;
  int rB = Bcnt[bn], rD = Dcnt[bn];
  int cB = min(rB, CAP), cD = min(rD, CAP);
  const int* pB = Bidx + (size_t)bn * CAP;
  const int* pD = Didx + (size_t)bn * CAP;
  float4 h0 = unpack4(nsb4[(size_t)bn * 64 + lane]);
  float4 sb = h0, sf = h0;
  for (int i = 0; i < cB; ++i) {
    int e = pB[i];
    float4 t = unpack4(eb4[((size_t)b * Ee + e) * 64 + lane]);
    sb.x += t.x; sb.y += t.y; sb.z += t.z; sb.w += t.w;
  }
  for (int i = 0; i < cD; ++i) {
    int e = pD[i];
    float4 t = unpack4(ef4[((size_t)b * Ee + e) * 64 + lane]);
    sf.x += t.x; sf.y += t.y; sf.z += t.z; sf.w += t.w;
  }
  float ib = 1.f / (1.f + (float)rB), idf = 1.f / (1.f + (float)rD);
  sb.x *= ib; sb.y *= ib; sb.z *= ib; sb.w *= ib;
  sf.x *= idf; sf.y *= idf; sf.z *= idf; sf.w *= idf;
  float4 prod = make_float4(sf.x*sb.x, sf.y*sb.y, sf.z*sb.z, sf.w*sb.w);
  size_t m = bn;
  Xfz4[m * 192 +   0 + lane] = pack4(sf);
  Xfz4[m * 192 +  64 + lane] = pack4(sb);
  Xfz4[m * 192 + 128 + lane] = pack4(prod);
}

// ---------- bf16 MFMA GEMM: BM=64, BN=64, 256 threads (4 waves 2x2), split-A option ----------
// 1D grid of 192*NBLK blocks; decode keeps all NBLK blocks of one m-panel on ONE XCD
// (ids differ by multiples of 8 -> same linear_id % 8 -> same XCD -> A-panel L2-resident).
#define EPI_MAXR 0
#define EPI_FZ   1
#define EPI_ZR   2
#define EPI_GRU  3

template<int EPI, int LAST, int SPLIT, int NBLK>
__global__ __launch_bounds__(256) void gemm_kernel(
    const unsigned short* __restrict__ A0, const unsigned short* __restrict__ A1,
    const unsigned short* __restrict__ WT,
    int M, int K,
    unsigned* __restrict__ gkey, const float* __restrict__ bfz,
    unsigned short* __restrict__ aggb, unsigned short* __restrict__ zbuf,
    unsigned short* __restrict__ rhb,
    float* __restrict__ outNBH,
    unsigned short* __restrict__ nsbout)
{
  __shared__ unsigned short As[64 * 64];
  __shared__ unsigned short Bs[64 * 64];
  __shared__ unsigned redk[2][64];
  int id = blockIdx.x;
  int kgrp = id >> 3;
  int n0 = (kgrp & (NBLK - 1)) * 64;
  int mb = (id & 7) + 8 * (kgrp / NBLK);
  int m0 = mb * 64;
  if (m0 >= M) return;
  int tid = threadIdx.x;
  int lane = tid & 63;
  int wid = __builtin_amdgcn_readfirstlane(tid >> 6);   // 0..3
  int wm = wid >> 1, wn = wid & 1;          // wave grid 2x2
  int p = lane >> 4;                        // quarter-wave
  int q = lane & 7;                         // 16B chunk within row
  int lr = lane >> 3;                       // row within 8-row stage group
  if (EPI == EPI_MAXR && tid < 128) redk[tid >> 6][tid & 63] = 0u;
  f32x4 acc[2][2] = {};
  for (int k0 = 0; k0 < K; k0 += 64) {
    const unsigned short* srcA = A0;
    int kA = k0, sA = K;
    if (SPLIT) { sA = 256; if (k0 >= 256) { srcA = A1; kA = k0 - 256; } }
    {
      int rl0 = wid * 16 + lr;
      int gm0 = m0 + rl0; if (gm0 > M - 1) gm0 = M - 1;
      GLL16(srcA + (size_t)gm0 * sA + kA + ((q ^ (rl0 & 7)) << 3), &As[(wid * 16) * 64]);
      int rl1 = rl0 + 8;
      int gm1 = m0 + rl1; if (gm1 > M - 1) gm1 = M - 1;
      GLL16(srcA + (size_t)gm1 * sA + kA + ((q ^ (rl1 & 7)) << 3), &As[(wid * 16 + 8) * 64]);
      GLL16(WT + (size_t)(n0 + rl0) * K + k0 + ((q ^ (rl0 & 7)) << 3), &Bs[(wid * 16) * 64]);
      GLL16(WT + (size_t)(n0 + rl1) * K + k0 + ((q ^ (rl1 & 7)) << 3), &Bs[(wid * 16 + 8) * 64]);
    }
    __syncthreads();
    #pragma unroll
    for (int kk = 0; kk < 64; kk += 32) {
      int cq = (kk >> 3) + p;
      int ra0 = wm * 32 + (lane & 15);
      int ra1 = ra0 + 16;
      int rb0 = wn * 32 + (lane & 15);
      int rb1 = rb0 + 16;
      bf16x8 a0 = *(const bf16x8*)&As[ra0 * 64 + ((cq ^ (ra0 & 7)) << 3)];
      bf16x8 a1 = *(const bf16x8*)&As[ra1 * 64 + ((cq ^ (ra1 & 7)) << 3)];
      bf16x8 b0 = *(const bf16x8*)&Bs[rb0 * 64 + ((cq ^ (rb0 & 7)) << 3)];
      bf16x8 b1 = *(const bf16x8*)&Bs[rb1 * 64 + ((cq ^ (rb1 & 7)) << 3)];
      acc[0][0] = __builtin_amdgcn_mfma_f32_16x16x32_bf16(a0, b0, acc[0][0], 0, 0, 0);
      acc[0][1] = __builtin_amdgcn_mfma_f32_16x16x32_bf16(a0, b1, acc[0][1], 0, 0, 0);
      acc[1][0] = __builtin_amdgcn_mfma_f32_16x16x32_bf16(a1, b0, acc[1][0], 0, 0, 0);
      acc[1][1] = __builtin_amdgcn_mfma_f32_16x16x32_bf16(a1, b1, acc[1][1], 0, 0, 0);
    }
    __syncthreads();
  }
  if (EPI == EPI_MAXR) {
    // per-block LDS key-max reduce over rows, then <=128 global atomics
    int blo = m0 / Nn;
    int bnd = (blo + 1) * Nn;               // row boundary to next batch
    #pragma unroll
    for (int ni = 0; ni < 2; ++ni) {
      unsigned um0 = 0u, um1 = 0u;
      #pragma unroll
      for (int mi = 0; mi < 2; ++mi)
      #pragma unroll
      for (int j = 0; j < 4; ++j) {
        int m = m0 + wm * 32 + mi * 16 + p * 4 + j;
        if (m < M) {
          unsigned k = fkey(acc[mi][ni][j]);
          if (m >= bnd) um1 = max(um1, k); else um0 = max(um0, k);
        }
      }
      int cl = wn * 32 + ni * 16 + (lane & 15);
      if (um0) atomicMax(&redk[0][cl], um0);
      if (um1) atomicMax(&redk[1][cl], um1);
    }
    __syncthreads();
    if (tid < 128) {
      int g = tid >> 6, cl = tid & 63;
      unsigned k = redk[g][cl];
      if (k) {
        int mm = (g == 0) ? m0 : (m0 + 63 < M ? m0 + 63 : M - 1);
        atomicMax(&gkey[(mm / Nn) * 256 + n0 + cl], k);
      }
    }
    return;
  }
  #pragma unroll
  for (int mi = 0; mi < 2; ++mi)
  #pragma unroll
  for (int ni = 0; ni < 2; ++ni)
  #pragma unroll
  for (int j = 0; j < 4; ++j) {
    int m = m0 + wm * 32 + mi * 16 + p * 4 + j;
    int c = n0 + wn * 32 + ni * 16 + (lane & 15);
    if (m >= M) continue;
    float v = acc[mi][ni][j];
    if (EPI == EPI_FZ) {
      float z = sigmoidf_(v + bfz[c]);
      float fw = b2f(A0[(size_t)m * K + c]);
      float bw = b2f(A0[(size_t)m * K + 256 + c]);
      aggb[(size_t)m * 256 + c] = f2b((1.f - z) * fw + z * bw);
    } else if (EPI == EPI_ZR) {
      float s = sigmoidf_(v);
      if (c < 256) {
        zbuf[(size_t)m * 256 + c] = f2b(s);
      } else {
        int cz = c - 256;
        // r*h with h from bf16 node state
        rhb[(size_t)m * 256 + cz] = f2b(s * b2f(nsbout[(size_t)m * 256 + cz]));
      }
    } else { // EPI_GRU — fully bf16 node state
      float t = tanhf(v);
      float zz = b2f(zbuf[(size_t)m * 256 + c]);
      float h = b2f(nsbout[(size_t)m * 256 + c]);
      float nh = (1.f - zz) * h + zz * t;
      nsbout[(size_t)m * 256 + c] = f2b(nh);
      if (LAST) {
        int bb = m / Nn, n = m - bb * Nn;
        outNBH[((size_t)n * Bb + bb) * 256 + c] = nh;   // (N,B,H) output, f32
      }
    }
  }
}

// ---------- decode max keys ----------
__global__ void maxfin_kernel(const unsigned* __restrict__ gkey, float* __restrict__ out) {
  int t = blockIdx.x * 256 + threadIdx.x;
  if (t >= Bb * Hh) return;
  unsigned k = gkey[t];
  unsigned u = (k & 0x80000000u) ? (k & 0x7fffffffu) : ~k;
  out[(size_t)Nn * Bb * Hh + t] = __uint_as_float(u);
}

extern "C" void kernel_launch(void* const* d_in, const int* in_sizes, int n_in,
                              void* d_out, int out_size, void* d_ws, size_t ws_size,
                              hipStream_t stream) {
  const float* in_ns   = (const float*)d_in[0];
  const float* in_ev   = (const float*)d_in[1];
  const float* in_n2e  = (const float*)d_in[2];   // (B,E,N)
  const float* in_e2n  = (const float*)d_in[3];   // (B,N,E)
  const float* in_wmax = (const float*)d_in[4];
  const float* in_wfz  = (const float*)d_in[5];
  const float* in_bfz  = (const float*)d_in[6];
  const float* in_wz   = (const float*)d_in[7];
  const float* in_wr   = (const float*)d_in[8];
  const float* in_wt   = (const float*)d_in[9];
  float* out = (float*)d_out;

  char* base = (char*)d_ws;
  size_t off = 0;
  auto alloc = [&](size_t bytes) -> void* {
    void* r = base + off;
    off = (off + bytes + 255) & ~(size_t)255;
    return r;
  };
  // counts + gkey + paircnt contiguous -> single memset
  int* cnts = (int*)alloc((size_t)(2 * BE + 2 * BN) * 4);   // 288000 B
  unsigned* gkey = (unsigned*)alloc(Bb * Hh * 4);            // 8192 B
  int* gpaircnt = (int*)alloc(256);                          // 1 int (padded)
  int* cntC = cnts;
  int* cntD = cnts + BE;
  int* cntA = cnts + BE + BN;
  int* cntB = cnts + BE + BN + BE;
  int* gpairs = (int*)alloc((size_t)PAIRBUF * 4);
  int* Aidx = (int*)alloc((size_t)BE * CAP * 4);
  int* Bidx = (int*)alloc((size_t)BN * CAP * 4);
  int* Cidx = (int*)alloc((size_t)BE * CAP * 4);
  int* Didx = (int*)alloc((size_t)BN * CAP * 4);
  unsigned short* nsb = (unsigned short*)alloc((size_t)Mrows * Hh * 2); // bf16 node state
  unsigned short* evb = (unsigned short*)alloc((size_t)BE * Hh * 2); // bf16
  unsigned short* eb = (unsigned short*)alloc((size_t)BE * Hh * 2);  // bf16
  unsigned short* ef = (unsigned short*)alloc((size_t)BE * Hh * 2);  // bf16
  unsigned short* Xfz = (unsigned short*)alloc((size_t)Mrows * 768 * 2);
  unsigned short* aggb = (unsigned short*)alloc((size_t)Mrows * 256 * 2); // bf16 agg
  unsigned short* rhb  = (unsigned short*)alloc((size_t)Mrows * 256 * 2); // bf16 r*h
  unsigned short* zbuf = (unsigned short*)alloc((size_t)Mrows * 256 * 2); // bf16 z
  unsigned short* WfzT  = (unsigned short*)alloc(256 * 768 * 2);
  unsigned short* WzrT  = (unsigned short*)alloc(512 * 512 * 2);
  unsigned short* WtT   = (unsigned short*)alloc(256 * 512 * 2);
  unsigned short* WmaxT = (unsigned short*)alloc(256 * 256 * 2);
  (void)ws_size; (void)in_sizes; (void)n_in; (void)out_size;

  hipMemsetAsync(cnts, 0,
                 (size_t)(2 * BE + 2 * BN) * 4 + (size_t)Bb * Hh * 4 + 256, stream);

  preprocess_kernel<<<13600, 256, 0, stream>>>(
      (const nf4*)in_n2e, (const nf4*)in_e2n,
      gpairs, gpaircnt,
      in_wfz, in_wz, in_wr, in_wt, in_wmax,
      WfzT, WzrT, WtT, WmaxT,
      in_ns, nsb, in_ev, evb);
  pairscatter_kernel<<<1024, 256, 0, stream>>>(
      gpairs, gpaircnt,
      Aidx, cntA, Didx, cntD, Bidx, cntB, Cidx, cntC);
  sort4_kernel<<<(2 * BE + 2 * BN + 255) / 256, 256, 0, stream>>>(
      Cidx, cntC, Didx, cntD, Aidx, cntA, Bidx, cntB);

  // 1D XCD-local grids: 192 m-panels (188 real + 4 pad) x NBLK n-blocks
  const int g4 = 192 * 4, g8 = 192 * 8;
  for (int hop = 0; hop < NHOPS; ++hop) {
    edge_kernel<<<BE / 4, 256, 0, stream>>>((const ushort4*)evb, (const ushort4*)nsb,
        Aidx, cntA, Cidx, cntC, (ushort4*)eb, (ushort4*)ef);
    node_kernel<<<BN / 4, 256, 0, stream>>>((const ushort4*)nsb,
        (const ushort4*)eb, (const ushort4*)ef,
        Bidx, cntB, Didx, cntD, (ushort4*)Xfz);
    gemm_kernel<EPI_FZ, 0, 0, 4><<<g4, 256, 0, stream>>>(Xfz, nullptr, WfzT, Mrows, 768,
        nullptr, in_bfz, aggb, nullptr, nullptr, nullptr, nullptr);
    gemm_kernel<EPI_ZR, 0, 1, 8><<<g8, 256, 0, stream>>>(nsb, aggb, WzrT, Mrows, 512,
        nullptr, nullptr, nullptr, zbuf, rhb, nullptr, nsb);
    if (hop < NHOPS - 1) {
      gemm_kernel<EPI_GRU, 0, 1, 4><<<g4, 256, 0, stream>>>(rhb, aggb, WtT, Mrows, 512,
          nullptr, nullptr, nullptr, zbuf, nullptr, nullptr, nsb);
    } else {
      gemm_kernel<EPI_GRU, 1, 1, 4><<<g4, 256, 0, stream>>>(rhb, aggb, WtT, Mrows, 512,
          nullptr, nullptr, nullptr, zbuf, nullptr, out, nsb);
    }
  }

  gemm_kernel<EPI_MAXR, 0, 0, 4><<<g4, 256, 0, stream>>>(nsb, nullptr, WmaxT, Mrows, 256,
      gkey, nullptr, nullptr, nullptr, nullptr, nullptr, nullptr);
  maxfin_kernel<<<(Bb * Hh + 255) / 256, 256, 0, stream>>>(gkey, out);
}

// Round 16
// 358.927 us; speedup vs baseline: 1.1941x; 1.1941x over previous
//
#include <hip/hip_runtime.h>
#include <hip/hip_bf16.h>
#include <stdint.h>

#define Bb 8
#define Nn 1500
#define Ee 3000
#define Hh 256
#define NHOPS 3
#define CAP 32
#define Mrows (Bb*Nn)      // 12000
#define BE (Bb*Ee)         // 24000
#define BN (Bb*Nn)         // 12000
#define TOTQ 9000000       // float4 per incidence matrix

typedef __bf16 bf16x8 __attribute__((ext_vector_type(8)));
typedef float f32x4 __attribute__((ext_vector_type(4)));
typedef float nf4 __attribute__((ext_vector_type(4)));   // native vec for nontemporal builtin

__device__ __forceinline__ float sigmoidf_(float x){ return 1.f/(1.f+__expf(-x)); }

__device__ __forceinline__ unsigned short f2b(float f){
  union { float f; unsigned int u; } x; x.f = f;
  unsigned int r = (x.u + 0x7fffu + ((x.u >> 16) & 1u)) >> 16;
  return (unsigned short)r;
}
__device__ __forceinline__ float b2f(unsigned short u){
  union { unsigned int u; float f; } x; x.u = ((unsigned int)u) << 16;
  return x.f;
}
__device__ __forceinline__ ushort4 pack4(float4 v){
  return make_ushort4(f2b(v.x), f2b(v.y), f2b(v.z), f2b(v.w));
}
__device__ __forceinline__ float4 unpack4(ushort4 u){
  return make_float4(b2f(u.x), b2f(u.y), b2f(u.z), b2f(u.w));
}
__device__ __forceinline__ unsigned fkey(float f){
  unsigned u = __float_as_uint(f);
  return (u & 0x80000000u) ? ~u : (u | 0x80000000u);
}

// async global->LDS, 16B per lane; LDS dest = uniform base + lane*16
#define GLL16(g, l) __builtin_amdgcn_global_load_lds( \
    (const __attribute__((address_space(1))) unsigned int*)(g), \
    (__attribute__((address_space(3))) unsigned int*)(l), 16, 0, 0)

// ---------- element-parallel sparse scan (atomic lists, sorted later) ----------
__device__ __forceinline__ void scan_proc(nf4 vv, int t,
    int* __restrict__ Aidx, int* __restrict__ cntA, int* __restrict__ Didx, int* __restrict__ cntD,
    int* __restrict__ Bidx, int* __restrict__ cntB, int* __restrict__ Cidx, int* __restrict__ cntC) {
  if (vv.x == 0.f && vv.y == 0.f && vv.z == 0.f && vv.w == 0.f) return;  // ~99% exit
  int *rowIdx, *rowCnt, *colIdx, *colCnt;
  int g, q, R, C;
  if (t < TOTQ) {
    rowIdx = Aidx; rowCnt = cntA; colIdx = Didx; colCnt = cntD;
    R = Ee; C = Nn;
    g = t / 375; q = t - g * 375;
  } else {
    int tt = t - TOTQ;
    rowIdx = Bidx; rowCnt = cntB; colIdx = Cidx; colCnt = cntC;
    R = Nn; C = Ee;
    g = tt / 750; q = tt - g * 750;
  }
  int b = g / R;
  int r = g - b * R;
  int cbase = q * 4;
  #pragma unroll
  for (int j = 0; j < 4; ++j) {
    float vj = (j == 0) ? vv.x : (j == 1) ? vv.y : (j == 2) ? vv.z : vv.w;
    if (vj != 0.f) {
      int c = cbase + j;
      int rs = atomicAdd(&rowCnt[g], 1);
      if (rs < CAP) rowIdx[(size_t)g * CAP + rs] = c;
      int cs = atomicAdd(&colCnt[b * C + c], 1);
      if (cs < CAP) colIdx[(size_t)(b * C + c) * CAP + cs] = r;
    }
  }
}

// ---------- preprocess megakernel (overlap latency-bound scan with BW prep) ----------
//  [0,8790)          both incidence scans, 8 quads/thread (18,000,000 quads)
//  [8790,11350)      weight prep (655360 elems)
//  [11350,12100)     in_ns f32 -> nsb bf16 (768,000 f4)
//  [12100,13600)     edge_vec f32 -> bf16 (1,536,000 f4)
__global__ void preprocess_kernel(const nf4* __restrict__ n2e4, const nf4* __restrict__ e2n4,
                                  int* __restrict__ Aidx, int* __restrict__ cntA,
                                  int* __restrict__ Didx, int* __restrict__ cntD,
                                  int* __restrict__ Bidx, int* __restrict__ cntB,
                                  int* __restrict__ Cidx, int* __restrict__ cntC,
                                  const float* __restrict__ Wfz, const float* __restrict__ Wz,
                                  const float* __restrict__ Wr, const float* __restrict__ Wt,
                                  const float* __restrict__ Wmax,
                                  unsigned short* __restrict__ WfzT, unsigned short* __restrict__ WzrT,
                                  unsigned short* __restrict__ WtT, unsigned short* __restrict__ WmaxT,
                                  const float* __restrict__ in_ns, unsigned short* __restrict__ nsb,
                                  const float* __restrict__ in_ev, unsigned short* __restrict__ evb) {
  int bx = blockIdx.x;
  if (bx < 8790) {
    int t0 = bx * 2048 + threadIdx.x;
    nf4 v[8];
    int ts[8];
    #pragma unroll
    for (int r2 = 0; r2 < 8; ++r2) {
      int t = t0 + r2 * 256;
      ts[r2] = t;
      const nf4* p = (t < TOTQ) ? (n2e4 + t) : (e2n4 + (t - TOTQ));
      if (t < 2 * TOTQ) v[r2] = __builtin_nontemporal_load(p);
      else { v[r2].x = 0.f; v[r2].y = 0.f; v[r2].z = 0.f; v[r2].w = 0.f; }
    }
    __builtin_amdgcn_sched_barrier(0);   // loads may not sink past this
    #pragma unroll
    for (int r2 = 0; r2 < 8; ++r2)
      scan_proc(v[r2], ts[r2], Aidx, cntA, Didx, cntD, Bidx, cntB, Cidx, cntC);
  } else if (bx < 11350) {
    int t = (bx - 8790) * 256 + threadIdx.x;
    if (t < 196608) {                       // WfzT': 256 n x 768 k (combined)
      int n = t / 768, k = t % 768;
      float v;
      if (k < 256)      v = Wfz[k * 256 + n] + Wfz[(k + 768) * 256 + n];
      else if (k < 512) v = Wfz[k * 256 + n] - Wfz[(k + 512) * 256 + n];
      else              v = Wfz[k * 256 + n];
      WfzT[t] = f2b(v);
    } else if (t < 458752) {                // WzrT: 512 j x 512 k
      int u = t - 196608;
      int j = u >> 9, k = u & 511;
      float v = (j < 256) ? Wz[k * 256 + j] : Wr[k * 256 + (j - 256)];
      WzrT[u] = f2b(v);
    } else if (t < 589824) {                // WtT: 256 n x 512 k
      int u = t - 458752;
      int n = u >> 9, k = u & 511;
      WtT[u] = f2b(Wt[k * 256 + n]);
    } else if (t < 655360) {                // WmaxT: 256 x 256
      int u = t - 589824;
      int n = u >> 8, k = u & 255;
      WmaxT[u] = f2b(Wmax[k * 256 + n]);
    }
  } else if (bx < 12100) {
    int t0 = (bx - 11350) * 1024 + threadIdx.x;   // 768000 f4
    #pragma unroll
    for (int r = 0; r < 4; ++r) {
      int t = t0 + r * 256;
      ((ushort4*)nsb)[t] = pack4(((const float4*)in_ns)[t]);
    }
  } else {
    int t0 = (bx - 12100) * 1024 + threadIdx.x;   // 1536000 f4
    #pragma unroll
    for (int r = 0; r < 4; ++r) {
      int t = t0 + r * 256;
      ((ushort4*)evb)[t] = pack4(((const float4*)in_ev)[t]);
    }
  }
}

__device__ __forceinline__ void sort_one(int* pp, int c) {
  if (c > CAP) c = CAP;
  int v[CAP];
  for (int j = 0; j < c; ++j) v[j] = pp[j];
  for (int j = 1; j < c; ++j) { int key = v[j]; int k = j - 1;
    while (k >= 0 && v[k] > key) { v[k+1] = v[k]; --k; } v[k+1] = key; }
  for (int j = 0; j < c; ++j) pp[j] = v[j];
}
// sorts all four list families (72000 lists)
__global__ void sort4_kernel(int* __restrict__ Cidx, const int* __restrict__ cntC,
                             int* __restrict__ Didx, const int* __restrict__ cntD,
                             int* __restrict__ Aidx, const int* __restrict__ cntA,
                             int* __restrict__ Bidx, const int* __restrict__ cntB) {
  int i = blockIdx.x * 256 + threadIdx.x;
  if (i < BE) sort_one(Cidx + (size_t)i * CAP, cntC[i]);
  else if (i < BE + BN) { int k = i - BE; sort_one(Didx + (size_t)k * CAP, cntD[k]); }
  else if (i < 2 * BE + BN) { int k = i - BE - BN; sort_one(Aidx + (size_t)k * CAP, cntA[k]); }
  else if (i < 2 * BE + 2 * BN) { int k = i - 2 * BE - BN; sort_one(Bidx + (size_t)k * CAP, cntB[k]); }
}

// ---------- per-hop: edge embedding (both directions), bf16 gathers, 4 edges/block ----------
__global__ void edge_kernel(const ushort4* __restrict__ evb4, const ushort4* __restrict__ nsb4,
                            const int* __restrict__ Aidx, const int* __restrict__ Acnt,
                            const int* __restrict__ Cidx, const int* __restrict__ Ccnt,
                            ushort4* __restrict__ eb4, ushort4* __restrict__ ef4) {
  int w = __builtin_amdgcn_readfirstlane((int)(threadIdx.x >> 6));
  int be = blockIdx.x * 4 + w;
  int lane = threadIdx.x & 63;
  int b = be / Ee;
  int cA = min(Acnt[be], CAP), cC = min(Ccnt[be], CAP);
  const int* pA = Aidx + (size_t)be * CAP;
  const int* pC = Cidx + (size_t)be * CAP;
  float4 ev = unpack4(evb4[(size_t)be * 64 + lane]);
  float4 sA = ev, sC = ev;
  for (int i = 0; i < cA; ++i) {
    int n = pA[i];
    float4 t = unpack4(nsb4[((size_t)b * Nn + n) * 64 + lane]);
    sA.x += t.x; sA.y += t.y; sA.z += t.z; sA.w += t.w;
  }
  for (int i = 0; i < cC; ++i) {
    int n = pC[i];
    float4 t = unpack4(nsb4[((size_t)b * Nn + n) * 64 + lane]);
    sC.x += t.x; sC.y += t.y; sC.z += t.z; sC.w += t.w;
  }
  eb4[(size_t)be * 64 + lane] = pack4(sA);
  ef4[(size_t)be * 64 + lane] = pack4(sC);
}

// ---------- per-hop: node aggregation + build Xfz (bf16 h from nsb) ----------
__global__ void node_kernel(const ushort4* __restrict__ nsb4,
                            const ushort4* __restrict__ eb4, const ushort4* __restrict__ ef4,
                            const int* __restrict__ Bidx, const int* __restrict__ Bcnt,
                            const int* __restrict__ Didx, const int* __restrict__ Dcnt,
                            ushort4* __restrict__ Xfz4) {
  int w = __builtin_amdgcn_readfirstlane((int)(threadIdx.x >> 6));
  int bn = blockIdx.x * 4 + w;
  int lane = threadIdx.x & 63;
  int b = bn / Nn;
  int rB = Bcnt[bn], rD = Dcnt[bn];
  int cB = min(rB, CAP), cD = min(rD, CAP);
  const int* pB = Bidx + (size_t)bn * CAP;
  const int* pD = Didx + (size_t)bn * CAP;
  float4 h0 = unpack4(nsb4[(size_t)bn * 64 + lane]);
  float4 sb = h0, sf = h0;
  for (int i = 0; i < cB; ++i) {
    int e = pB[i];
    float4 t = unpack4(eb4[((size_t)b * Ee + e) * 64 + lane]);
    sb.x += t.x; sb.y += t.y; sb.z += t.z; sb.w += t.w;
  }
  for (int i = 0; i < cD; ++i) {
    int e = pD[i];
    float4 t = unpack4(ef4[((size_t)b * Ee + e) * 64 + lane]);
    sf.x += t.x; sf.y += t.y; sf.z += t.z; sf.w += t.w;
  }
  float ib = 1.f / (1.f + (float)rB), idf = 1.f / (1.f + (float)rD);
  sb.x *= ib; sb.y *= ib; sb.z *= ib; sb.w *= ib;
  sf.x *= idf; sf.y *= idf; sf.z *= idf; sf.w *= idf;
  float4 prod = make_float4(sf.x*sb.x, sf.y*sb.y, sf.z*sb.z, sf.w*sb.w);
  size_t m = bn;
  Xfz4[m * 192 +   0 + lane] = pack4(sf);
  Xfz4[m * 192 +  64 + lane] = pack4(sb);
  Xfz4[m * 192 + 128 + lane] = pack4(prod);
}

// ---------- bf16 MFMA GEMM: BM=64, BN=64, 256 threads (4 waves 2x2), split-A option ----------
// 1D grid of 192*NBLK blocks; decode keeps all NBLK blocks of one m-panel on ONE XCD
// (ids differ by multiples of 8 -> same linear_id % 8 -> same XCD -> A-panel L2-resident).
#define EPI_MAXR 0
#define EPI_FZ   1
#define EPI_ZR   2
#define EPI_GRU  3

template<int EPI, int LAST, int SPLIT, int NBLK>
__global__ __launch_bounds__(256) void gemm_kernel(
    const unsigned short* __restrict__ A0, const unsigned short* __restrict__ A1,
    const unsigned short* __restrict__ WT,
    int M, int K,
    unsigned* __restrict__ gkey, const float* __restrict__ bfz,
    unsigned short* __restrict__ aggb, unsigned short* __restrict__ zbuf,
    unsigned short* __restrict__ rhb,
    float* __restrict__ outNBH,
    unsigned short* __restrict__ nsbout)
{
  __shared__ unsigned short As[64 * 64];
  __shared__ unsigned short Bs[64 * 64];
  __shared__ unsigned redk[2][64];
  int id = blockIdx.x;
  int kgrp = id >> 3;
  int n0 = (kgrp & (NBLK - 1)) * 64;
  int mb = (id & 7) + 8 * (kgrp / NBLK);
  int m0 = mb * 64;
  if (m0 >= M) return;
  int tid = threadIdx.x;
  int lane = tid & 63;
  int wid = __builtin_amdgcn_readfirstlane(tid >> 6);   // 0..3
  int wm = wid >> 1, wn = wid & 1;          // wave grid 2x2
  int p = lane >> 4;                        // quarter-wave
  int q = lane & 7;                         // 16B chunk within row
  int lr = lane >> 3;                       // row within 8-row stage group
  if (EPI == EPI_MAXR && tid < 128) redk[tid >> 6][tid & 63] = 0u;
  f32x4 acc[2][2] = {};
  for (int k0 = 0; k0 < K; k0 += 64) {
    const unsigned short* srcA = A0;
    int kA = k0, sA = K;
    if (SPLIT) { sA = 256; if (k0 >= 256) { srcA = A1; kA = k0 - 256; } }
    {
      int rl0 = wid * 16 + lr;
      int gm0 = m0 + rl0; if (gm0 > M - 1) gm0 = M - 1;
      GLL16(srcA + (size_t)gm0 * sA + kA + ((q ^ (rl0 & 7)) << 3), &As[(wid * 16) * 64]);
      int rl1 = rl0 + 8;
      int gm1 = m0 + rl1; if (gm1 > M - 1) gm1 = M - 1;
      GLL16(srcA + (size_t)gm1 * sA + kA + ((q ^ (rl1 & 7)) << 3), &As[(wid * 16 + 8) * 64]);
      GLL16(WT + (size_t)(n0 + rl0) * K + k0 + ((q ^ (rl0 & 7)) << 3), &Bs[(wid * 16) * 64]);
      GLL16(WT + (size_t)(n0 + rl1) * K + k0 + ((q ^ (rl1 & 7)) << 3), &Bs[(wid * 16 + 8) * 64]);
    }
    __syncthreads();
    #pragma unroll
    for (int kk = 0; kk < 64; kk += 32) {
      int cq = (kk >> 3) + p;
      int ra0 = wm * 32 + (lane & 15);
      int ra1 = ra0 + 16;
      int rb0 = wn * 32 + (lane & 15);
      int rb1 = rb0 + 16;
      bf16x8 a0 = *(const bf16x8*)&As[ra0 * 64 + ((cq ^ (ra0 & 7)) << 3)];
      bf16x8 a1 = *(const bf16x8*)&As[ra1 * 64 + ((cq ^ (ra1 & 7)) << 3)];
      bf16x8 b0 = *(const bf16x8*)&Bs[rb0 * 64 + ((cq ^ (rb0 & 7)) << 3)];
      bf16x8 b1 = *(const bf16x8*)&Bs[rb1 * 64 + ((cq ^ (rb1 & 7)) << 3)];
      acc[0][0] = __builtin_amdgcn_mfma_f32_16x16x32_bf16(a0, b0, acc[0][0], 0, 0, 0);
      acc[0][1] = __builtin_amdgcn_mfma_f32_16x16x32_bf16(a0, b1, acc[0][1], 0, 0, 0);
      acc[1][0] = __builtin_amdgcn_mfma_f32_16x16x32_bf16(a1, b0, acc[1][0], 0, 0, 0);
      acc[1][1] = __builtin_amdgcn_mfma_f32_16x16x32_bf16(a1, b1, acc[1][1], 0, 0, 0);
    }
    __syncthreads();
  }
  if (EPI == EPI_MAXR) {
    // per-block LDS key-max reduce over rows, then <=128 global atomics
    int blo = m0 / Nn;
    int bnd = (blo + 1) * Nn;               // row boundary to next batch
    #pragma unroll
    for (int ni = 0; ni < 2; ++ni) {
      unsigned um0 = 0u, um1 = 0u;
      #pragma unroll
      for (int mi = 0; mi < 2; ++mi)
      #pragma unroll
      for (int j = 0; j < 4; ++j) {
        int m = m0 + wm * 32 + mi * 16 + p * 4 + j;
        if (m < M) {
          unsigned k = fkey(acc[mi][ni][j]);
          if (m >= bnd) um1 = max(um1, k); else um0 = max(um0, k);
        }
      }
      int cl = wn * 32 + ni * 16 + (lane & 15);
      if (um0) atomicMax(&redk[0][cl], um0);
      if (um1) atomicMax(&redk[1][cl], um1);
    }
    __syncthreads();
    if (tid < 128) {
      int g = tid >> 6, cl = tid & 63;
      unsigned k = redk[g][cl];
      if (k) {
        int mm = (g == 0) ? m0 : (m0 + 63 < M ? m0 + 63 : M - 1);
        atomicMax(&gkey[(mm / Nn) * 256 + n0 + cl], k);
      }
    }
    return;
  }
  #pragma unroll
  for (int mi = 0; mi < 2; ++mi)
  #pragma unroll
  for (int ni = 0; ni < 2; ++ni)
  #pragma unroll
  for (int j = 0; j < 4; ++j) {
    int m = m0 + wm * 32 + mi * 16 + p * 4 + j;
    int c = n0 + wn * 32 + ni * 16 + (lane & 15);
    if (m >= M) continue;
    float v = acc[mi][ni][j];
    if (EPI == EPI_FZ) {
      float z = sigmoidf_(v + bfz[c]);
      float fw = b2f(A0[(size_t)m * K + c]);
      float bw = b2f(A0[(size_t)m * K + 256 + c]);
      aggb[(size_t)m * 256 + c] = f2b((1.f - z) * fw + z * bw);
    } else if (EPI == EPI_ZR) {
      float s = sigmoidf_(v);
      if (c < 256) {
        zbuf[(size_t)m * 256 + c] = f2b(s);
      } else {
        int cz = c - 256;
        // r*h with h from bf16 node state
        rhb[(size_t)m * 256 + cz] = f2b(s * b2f(nsbout[(size_t)m * 256 + cz]));
      }
    } else { // EPI_GRU — fully bf16 node state
      float t = tanhf(v);
      float zz = b2f(zbuf[(size_t)m * 256 + c]);
      float h = b2f(nsbout[(size_t)m * 256 + c]);
      float nh = (1.f - zz) * h + zz * t;
      nsbout[(size_t)m * 256 + c] = f2b(nh);
      if (LAST) {
        int bb = m / Nn, n = m - bb * Nn;
        outNBH[((size_t)n * Bb + bb) * 256 + c] = nh;   // (N,B,H) output, f32
      }
    }
  }
}

// ---------- decode max keys ----------
__global__ void maxfin_kernel(const unsigned* __restrict__ gkey, float* __restrict__ out) {
  int t = blockIdx.x * 256 + threadIdx.x;
  if (t >= Bb * Hh) return;
  unsigned k = gkey[t];
  unsigned u = (k & 0x80000000u) ? (k & 0x7fffffffu) : ~k;
  out[(size_t)Nn * Bb * Hh + t] = __uint_as_float(u);
}

extern "C" void kernel_launch(void* const* d_in, const int* in_sizes, int n_in,
                              void* d_out, int out_size, void* d_ws, size_t ws_size,
                              hipStream_t stream) {
  const float* in_ns   = (const float*)d_in[0];
  const float* in_ev   = (const float*)d_in[1];
  const float* in_n2e  = (const float*)d_in[2];   // (B,E,N)
  const float* in_e2n  = (const float*)d_in[3];   // (B,N,E)
  const float* in_wmax = (const float*)d_in[4];
  const float* in_wfz  = (const float*)d_in[5];
  const float* in_bfz  = (const float*)d_in[6];
  const float* in_wz   = (const float*)d_in[7];
  const float* in_wr   = (const float*)d_in[8];
  const float* in_wt   = (const float*)d_in[9];
  float* out = (float*)d_out;

  char* base = (char*)d_ws;
  size_t off = 0;
  auto alloc = [&](size_t bytes) -> void* {
    void* r = base + off;
    off = (off + bytes + 255) & ~(size_t)255;
    return r;
  };
  // counts + gkey contiguous -> single memset (288000 % 256 == 0)
  int* cnts = (int*)alloc((size_t)(2 * BE + 2 * BN) * 4);   // 288000 B
  unsigned* gkey = (unsigned*)alloc(Bb * Hh * 4);            // 8192 B
  int* cntC = cnts;
  int* cntD = cnts + BE;
  int* cntA = cnts + BE + BN;
  int* cntB = cnts + BE + BN + BE;
  int* Aidx = (int*)alloc((size_t)BE * CAP * 4);
  int* Bidx = (int*)alloc((size_t)BN * CAP * 4);
  int* Cidx = (int*)alloc((size_t)BE * CAP * 4);
  int* Didx = (int*)alloc((size_t)BN * CAP * 4);
  unsigned short* nsb = (unsigned short*)alloc((size_t)Mrows * Hh * 2); // bf16 node state
  unsigned short* evb = (unsigned short*)alloc((size_t)BE * Hh * 2); // bf16
  unsigned short* eb = (unsigned short*)alloc((size_t)BE * Hh * 2);  // bf16
  unsigned short* ef = (unsigned short*)alloc((size_t)BE * Hh * 2);  // bf16
  unsigned short* Xfz = (unsigned short*)alloc((size_t)Mrows * 768 * 2);
  unsigned short* aggb = (unsigned short*)alloc((size_t)Mrows * 256 * 2); // bf16 agg
  unsigned short* rhb  = (unsigned short*)alloc((size_t)Mrows * 256 * 2); // bf16 r*h
  unsigned short* zbuf = (unsigned short*)alloc((size_t)Mrows * 256 * 2); // bf16 z
  unsigned short* WfzT  = (unsigned short*)alloc(256 * 768 * 2);
  unsigned short* WzrT  = (unsigned short*)alloc(512 * 512 * 2);
  unsigned short* WtT   = (unsigned short*)alloc(256 * 512 * 2);
  unsigned short* WmaxT = (unsigned short*)alloc(256 * 256 * 2);
  (void)ws_size; (void)in_sizes; (void)n_in; (void)out_size;

  hipMemsetAsync(cnts, 0, (size_t)(2 * BE + 2 * BN) * 4 + (size_t)Bb * Hh * 4, stream);

  preprocess_kernel<<<13600, 256, 0, stream>>>(
      (const nf4*)in_n2e, (const nf4*)in_e2n,
      Aidx, cntA, Didx, cntD, Bidx, cntB, Cidx, cntC,
      in_wfz, in_wz, in_wr, in_wt, in_wmax,
      WfzT, WzrT, WtT, WmaxT,
      in_ns, nsb, in_ev, evb);
  sort4_kernel<<<(2 * BE + 2 * BN + 255) / 256, 256, 0, stream>>>(
      Cidx, cntC, Didx, cntD, Aidx, cntA, Bidx, cntB);

  // 1D XCD-local grids: 192 m-panels (188 real + 4 pad) x NBLK n-blocks
  const int g4 = 192 * 4, g8 = 192 * 8;
  for (int hop = 0; hop < NHOPS; ++hop) {
    edge_kernel<<<BE / 4, 256, 0, stream>>>((const ushort4*)evb, (const ushort4*)nsb,
        Aidx, cntA, Cidx, cntC, (ushort4*)eb, (ushort4*)ef);
    node_kernel<<<BN / 4, 256, 0, stream>>>((const ushort4*)nsb,
        (const ushort4*)eb, (const ushort4*)ef,
        Bidx, cntB, Didx, cntD, (ushort4*)Xfz);
    gemm_kernel<EPI_FZ, 0, 0, 4><<<g4, 256, 0, stream>>>(Xfz, nullptr, WfzT, Mrows, 768,
        nullptr, in_bfz, aggb, nullptr, nullptr, nullptr, nullptr);
    gemm_kernel<EPI_ZR, 0, 1, 8><<<g8, 256, 0, stream>>>(nsb, aggb, WzrT, Mrows, 512,
        nullptr, nullptr, nullptr, zbuf, rhb, nullptr, nsb);
    if (hop < NHOPS - 1) {
      gemm_kernel<EPI_GRU, 0, 1, 4><<<g4, 256, 0, stream>>>(rhb, aggb, WtT, Mrows, 512,
          nullptr, nullptr, nullptr, zbuf, nullptr, nullptr, nsb);
    } else {
      gemm_kernel<EPI_GRU, 1, 1, 4><<<g4, 256, 0, stream>>>(rhb, aggb, WtT, Mrows, 512,
          nullptr, nullptr, nullptr, zbuf, nullptr, out, nsb);
    }
  }

  gemm_kernel<EPI_MAXR, 0, 0, 4><<<g4, 256, 0, stream>>>(nsb, nullptr, WmaxT, Mrows, 256,
      gkey, nullptr, nullptr, nullptr, nullptr, nullptr, nullptr);
  maxfin_kernel<<<(Bb * Hh + 255) / 256, 256, 0, stream>>>(gkey, out);
}